// Round 5
// baseline (90449.097 us; speedup 1.0000x reference)
//
#include <hip/hip_runtime.h>
#include <cstddef>

#define T_STEPS 4096
#define H_DIM   4096
#define IN_DIM  1024
#define O_DIM   512
#define N_WG    256   // 1 block/CU -- launch shape proven in prior rounds

typedef unsigned long long u64;

__device__ __forceinline__ float sigmoid_f(float v) {
    v = fminf(fmaxf(v, -30.f), 30.f);
    return 1.f / (1.f + __expf(-v));
}
__device__ __forceinline__ float tanh_f(float v) {
    v = fminf(fmaxf(v, -15.f), 15.f);
    float e = __expf(2.f * v);
    return (e - 1.f) / (e + 1.f);
}

// Keep W_rec register rows opaque so the scheduler can't sink/remat the
// global loads into the t-loop (prior rounds: remat = 84 MB/step L2 re-reads).
#define PIN4(v) asm volatile("" : "+v"(v.x), "+v"(v.y), "+v"(v.z), "+v"(v.w))

// fp32 -> packed bf16x2 (round-to-nearest-even), and unpack helpers.
__device__ __forceinline__ unsigned pack_bf2(float a, float b) {
    unsigned ua = __float_as_uint(a), ub = __float_as_uint(b);
    ua = (ua + 0x7fffu + ((ua >> 16) & 1u)) >> 16;
    ub = (ub + 0x7fffu + ((ub >> 16) & 1u)) & 0xffff0000u;
    return ua | ub;
}
__device__ __forceinline__ float bf_lo(unsigned u) { return __uint_as_float(u << 16); }
__device__ __forceinline__ float bf_hi(unsigned u) { return __uint_as_float(u & 0xffff0000u); }

// R11: PIPELINED DISCOVERY. Ladder calibration: R7->R8 removed ~2 agent-scope
// hops and saved 4.05 us/step => contended hop ~1.8-2 us. R9 (less poll
// traffic) and R10 (coalesced publish; WRITE 557->164 MB but dur flat) prove
// VOLUME is not the currency -- serialized hops and discovery lag are.
//   (a) 3-deep ping-pong poll (sA/sB/sC): >=2 sweeps always in flight;
//       checking the oldest waits vmcnt(16) while newer sweeps sample.
//       Discovery lag ~1.5RT -> ~0.5RT. No s_sleep.
//   (b) first two sweeps for gen t+1 issued RIGHT AFTER the publish store,
//       so sampling runs during the slack work, not after it.
//   (c) x prefetched 2 steps ahead (double-buffered LDS): the fresh-4KB HBM
//       fetch no longer pokes into the serial chain.
//   (d) publish reverted to R8 per-wave lane0/lane1 immediate stores
//       (earliest visibility; R10's gather cost +0.15us/step; writes proven
//       free at 557 MB).
// Gen-parity safety unchanged: buf[t&1] only ever holds gens t, t+2, ...;
// '== t' polling can never miss or skip a generation. Stale sweeps into the
// next-gen buffer just fail the check and recycle.
__global__ __launch_bounds__(512, 2) void snn_persistent(
    const float* __restrict__ x, const float* __restrict__ Win,
    const float* __restrict__ Wrec, const float* __restrict__ Wout,
    const float* __restrict__ gbias, float* __restrict__ y,
    u64* __restrict__ hbuf)
{
    __shared__ __attribute__((aligned(16))) float h_lds[H_DIM];   // 16 KB
    __shared__ __attribute__((aligned(16))) float xb0[IN_DIM];    // 4 KB
    __shared__ __attribute__((aligned(16))) float xb1[IN_DIM];    // 4 KB
    __shared__ float osc[8][2];

    const int tid = threadIdx.x;
    const int w   = tid >> 6;     // wave 0..7
    const int l   = tid & 63;     // lane
    const int wg  = blockIdx.x;   // 0..255

    const int rowA  = wg * 16 + w;      // both W_rec rows register-resident
    const int rowB  = rowA + 8;
    const int orow0 = wg * 2;
    const int orow1 = orow0 + 1;

    // ---- one-time: 32 register-resident W_rec row-slices (128 VGPRs) ----
    const float4* pa = (const float4*)Wrec + (size_t)rowA * (H_DIM / 4) + l;
    const float4* pb = (const float4*)Wrec + (size_t)rowB * (H_DIM / 4) + l;
#define WRL(k) float4 wa##k = pa[(k) * 64]; PIN4(wa##k); \
               float4 wb##k = pb[(k) * 64]; PIN4(wb##k);
    WRL(0) WRL(1) WRL(2) WRL(3) WRL(4) WRL(5) WRL(6) WRL(7)
    WRL(8) WRL(9) WRL(10) WRL(11) WRL(12) WRL(13) WRL(14) WRL(15)
#undef WRL

    const float4* pia = (const float4*)Win + (size_t)rowA * (IN_DIM / 4) + l;
    const float4* pib = (const float4*)Win + (size_t)rowB * (IN_DIM / 4) + l;
    unsigned wiA[8], wiB[8];
    #pragma unroll
    for (int k = 0; k < 4; ++k) {
        float4 va = pia[k * 64], vb = pib[k * 64];
        wiA[2 * k]     = pack_bf2(va.x, va.y);
        wiA[2 * k + 1] = pack_bf2(va.z, va.w);
        wiB[2 * k]     = pack_bf2(vb.x, vb.y);
        wiB[2 * k + 1] = pack_bf2(vb.z, vb.w);
    }

    const float* po0 = Wout + (size_t)orow0 * H_DIM + tid;
    const float* po1 = Wout + (size_t)orow1 * H_DIM + tid;
    unsigned woP0[4], woP1[4];
    #pragma unroll
    for (int j = 0; j < 4; ++j) {
        woP0[j] = pack_bf2(po0[1024 * j], po0[1024 * j + 512]);
        woP1[j] = pack_bf2(po1[1024 * j], po1[1024 * j + 512]);
    }

    const float gbA  = gbias[rowA];
    const float gbB  = gbias[rowB];
    const float leak = 0.1f;

    u64* b0 = hbuf;          // holds h_t for even t (memset 0 => gen 0, h0=0)
    u64* b1 = hbuf + H_DIM;  // holds h_t for odd t

    float iA, iB;            // input currents, computed one step ahead
#define COMPUTE_I(XB) do { iA = 0.f; iB = 0.f;                                  \
        const float4* x4_ = (const float4*)(XB);                                \
        _Pragma("unroll")                                                       \
        for (int k = 0; k < 4; ++k) {                                           \
            float4 xv = x4_[k * 64 + l];                                        \
            unsigned a0 = wiA[2 * k], a1 = wiA[2 * k + 1];                      \
            unsigned c0 = wiB[2 * k], c1 = wiB[2 * k + 1];                      \
            iA = fmaf(bf_lo(a0), xv.x, fmaf(bf_hi(a0), xv.y,                    \
                 fmaf(bf_lo(a1), xv.z, fmaf(bf_hi(a1), xv.w, iA))));            \
            iB = fmaf(bf_lo(c0), xv.x, fmaf(bf_hi(c0), xv.y,                    \
                 fmaf(bf_lo(c1), xv.z, fmaf(bf_hi(c1), xv.w, iB))));            \
        }                                                                       \
        _Pragma("unroll")                                                       \
        for (int off = 32; off; off >>= 1) {                                    \
            iA += __shfl_xor(iA, off); iB += __shfl_xor(iB, off);               \
        } } while (0)

    // ---- pipelined 3-deep poll machinery (48 VGPRs of sweep buffers) ----
    u64 sA[8], sB[8], sC[8];
    float vals[8];           // this thread's 8 accepted h values
#define ISSUE(S, SRC) { _Pragma("unroll")                                       \
        for (int k = 0; k < 8; ++k)                                             \
            (S)[k] = __hip_atomic_load(&(SRC)[tid + (k << 9)],                  \
                     __ATOMIC_RELAXED, __HIP_MEMORY_SCOPE_AGENT); }
#define CHK(S, GEN, OK) { OK = 1u; _Pragma("unroll")                            \
        for (int k = 0; k < 8; ++k)                                             \
            OK &= ((unsigned)((S)[k] >> 32) == (GEN)) ? 1u : 0u; }
#define TAKE(S) { _Pragma("unroll")                                             \
        for (int k = 0; k < 8; ++k)                                             \
            vals[k] = __uint_as_float((unsigned)(S)[k]); }
    // assumes sA,sB already in flight at SRC
#define POLL_PIPE(SRC, GEN) do { unsigned ok_;                                  \
        for (;;) {                                                              \
            ISSUE(sC, SRC); CHK(sA, GEN, ok_); if (ok_) { TAKE(sA); break; }    \
            ISSUE(sA, SRC); CHK(sB, GEN, ok_); if (ok_) { TAKE(sB); break; }    \
            ISSUE(sB, SRC); CHK(sC, GEN, ok_); if (ok_) { TAKE(sC); break; }    \
        } } while (0)

    // W_out partials straight from vals[] registers (slot k = tid + 512k, so
    // vals[2j]/vals[2j+1] are exactly h[tid+1024j]/h[tid+1024j+512]).
#define WOUT_OSC() do { float p0 = 0.f, p1 = 0.f;                               \
        _Pragma("unroll")                                                       \
        for (int j = 0; j < 4; ++j) {                                           \
            p0 = fmaf(bf_lo(woP0[j]), vals[2 * j],                              \
                 fmaf(bf_hi(woP0[j]), vals[2 * j + 1], p0));                    \
            p1 = fmaf(bf_lo(woP1[j]), vals[2 * j],                              \
                 fmaf(bf_hi(woP1[j]), vals[2 * j + 1], p1));                    \
        }                                                                       \
        _Pragma("unroll")                                                       \
        for (int off = 32; off; off >>= 1) {                                    \
            p0 += __shfl_xor(p0, off); p1 += __shfl_xor(p1, off);               \
        }                                                                       \
        if (l == 0) { osc[w][0] = p0; osc[w][1] = p1; } } while (0)

    // ---- prologue: x_0,x_1 staged (2-ahead pipeline), I(t=0), sweeps up ----
    if (tid < 256) {
        ((float4*)xb0)[tid] = ((const float4*)x)[tid];
        ((float4*)xb1)[tid] = ((const float4*)(x + IN_DIM))[tid];
    }
    __syncthreads();
    COMPUTE_I(xb0);
    ISSUE(sA, b0); ISSUE(sB, b0);

    #pragma unroll 1
    for (int t = 0; t < T_STEPS; ++t) {
        const u64* src = (t & 1) ? b1 : b0;
        u64*       dst = (t & 1) ? b0 : b1;

        // ---- pipelined poll: the grid barrier AND the h staging load ----
        POLL_PIPE(src, (unsigned)t);
        #pragma unroll
        for (int k = 0; k < 8; ++k) h_lds[tid + (k << 9)] = vals[k];
        __syncthreads();                          // S1: h_t fully staged

        // ---- CRITICAL PATH: W_rec . h -> reduce -> nonlinearity -> publish
        float4 a = make_float4(0.f, 0.f, 0.f, 0.f);
        float4 b = make_float4(0.f, 0.f, 0.f, 0.f);
        {
            const float4* h4 = (const float4*)h_lds;
#define WRF(k) { float4 hv = h4[(k) * 64 + l];                                  \
                 a.x = fmaf(wa##k.x, hv.x, a.x); a.y = fmaf(wa##k.y, hv.y, a.y);\
                 a.z = fmaf(wa##k.z, hv.z, a.z); a.w = fmaf(wa##k.w, hv.w, a.w);\
                 b.x = fmaf(wb##k.x, hv.x, b.x); b.y = fmaf(wb##k.y, hv.y, b.y);\
                 b.z = fmaf(wb##k.z, hv.z, b.z); b.w = fmaf(wb##k.w, hv.w, b.w); }
            WRF(0) WRF(1) WRF(2) WRF(3) WRF(4) WRF(5) WRF(6) WRF(7)
            WRF(8) WRF(9) WRF(10) WRF(11) WRF(12) WRF(13) WRF(14) WRF(15)
#undef WRF
        }
        float rA = (a.x + a.y) + (a.z + a.w);
        float rB = (b.x + b.y) + (b.z + b.w);
        #pragma unroll
        for (int off = 32; off; off >>= 1) {
            rA += __shfl_xor(rA, off);
            rB += __shfl_xor(rB, off);
        }
        if (l == 0) {                             // R8-style immediate publish
            float gA = sigmoid_f(gbA + rA);
            float zA = tanh_f(fmaf(gA, rA, iA));
            float hA = h_lds[rowA];
            __hip_atomic_store(&dst[rowA],
                ((u64)(unsigned)(t + 1) << 32) |
                    (u64)__float_as_uint(fmaf(leak, zA - hA, hA)),
                __ATOMIC_RELAXED, __HIP_MEMORY_SCOPE_AGENT);
        } else if (l == 1) {
            float gB = sigmoid_f(gbB + rB);
            float zB = tanh_f(fmaf(gB, rB, iB));
            float hB = h_lds[rowB];
            __hip_atomic_store(&dst[rowB],
                ((u64)(unsigned)(t + 1) << 32) |
                    (u64)__float_as_uint(fmaf(leak, zB - hB, hB)),
                __ATOMIC_RELAXED, __HIP_MEMORY_SCOPE_AGENT);
        }

        // start sampling gen t+1 NOW -- runs during all the slack below
        ISSUE(sA, dst); ISSUE(sB, dst);

        // ---- SLACK: x two-ahead, W_out partials, y, next W_in ----
        if (t + 2 < T_STEPS && tid < 256) {
            float* xbn = (t & 1) ? xb1 : xb0;     // buffer for x_{t+2}
            ((float4*)xbn)[tid] =
                ((const float4*)(x + (size_t)(t + 2) * IN_DIM))[tid];
        }
        if (t >= 1) WOUT_OSC();                   // y_{t-1} partials from vals
        __syncthreads();                          // S2: osc + x buffers ready
        if (t >= 1 && tid == 0) {
            float s0 = 0.f, s1 = 0.f;
            #pragma unroll
            for (int q = 0; q < 8; ++q) { s0 += osc[q][0]; s1 += osc[q][1]; }
            y[(size_t)(t - 1) * O_DIM + orow0] = s0;
            y[(size_t)(t - 1) * O_DIM + orow1] = s1;
        }
        if (t + 1 < T_STEPS) {                    // I for t+1 from x_{t+1}
            const float* xbc = (t & 1) ? xb0 : xb1;
            COMPUTE_I(xbc);
        }
    }

    // ---- epilogue: y[T-1] = W_out . h_T (gen T sits in b0, T even; sA/sB
    // for b0 already in flight from the last iteration) ----
    POLL_PIPE(b0, (unsigned)T_STEPS);
    __syncthreads();   // ensure tid0 finished reading osc for y[T-2]
    WOUT_OSC();
    __syncthreads();
    if (tid == 0) {
        float s0 = 0.f, s1 = 0.f;
        #pragma unroll
        for (int q = 0; q < 8; ++q) { s0 += osc[q][0]; s1 += osc[q][1]; }
        y[(size_t)(T_STEPS - 1) * O_DIM + orow0] = s0;
        y[(size_t)(T_STEPS - 1) * O_DIM + orow1] = s1;
    }
}

extern "C" void kernel_launch(void* const* d_in, const int* in_sizes, int n_in,
                              void* d_out, int out_size, void* d_ws, size_t ws_size,
                              hipStream_t stream) {
    const float* x     = (const float*)d_in[0];
    const float* Win   = (const float*)d_in[1];
    const float* Wrec  = (const float*)d_in[2];
    const float* Wout  = (const float*)d_in[3];
    const float* gbias = (const float*)d_in[4];
    float* y = (float*)d_out;

    u64* hbuf = (u64*)d_ws;  // 2 x 4096 x (gen<<32 | h-bits) = 64 KB

    // ws is re-poisoned before every replay: zero => h0 = 0 with gen 0.
    hipMemsetAsync(d_ws, 0, 2 * H_DIM * sizeof(u64), stream);

    void* args[] = { (void*)&x, (void*)&Win, (void*)&Wrec, (void*)&Wout,
                     (void*)&gbias, (void*)&y, (void*)&hbuf };
    hipLaunchCooperativeKernel((const void*)snn_persistent, dim3(N_WG), dim3(512),
                               args, 0, stream);
}

// Round 6
// 19532.077 us; speedup vs baseline: 4.6308x; 4.6308x over previous
//
#include <hip/hip_runtime.h>
#include <cstddef>

#define T_STEPS 4096
#define H_DIM   4096
#define IN_DIM  1024
#define O_DIM   512
#define N_WG    256   // 1 block/CU -- launch shape proven in prior rounds
#define N_REP   8     // h replicas: per-line consumer fan-out 256 -> 32

typedef unsigned long long u64;

__device__ __forceinline__ float sigmoid_f(float v) {
    v = fminf(fmaxf(v, -30.f), 30.f);
    return 1.f / (1.f + __expf(-v));
}
__device__ __forceinline__ float tanh_f(float v) {
    v = fminf(fmaxf(v, -15.f), 15.f);
    float e = __expf(2.f * v);
    return (e - 1.f) / (e + 1.f);
}

// Keep W_rec register rows opaque so the scheduler can't sink/remat the
// global loads into the t-loop (prior rounds: remat = 84 MB/step L2 re-reads).
#define PIN4(v) asm volatile("" : "+v"(v.x), "+v"(v.y), "+v"(v.z), "+v"(v.w))

// fp32 -> packed bf16x2 (round-to-nearest-even), and unpack helpers.
__device__ __forceinline__ unsigned pack_bf2(float a, float b) {
    unsigned ua = __float_as_uint(a), ub = __float_as_uint(b);
    ua = (ua + 0x7fffu + ((ua >> 16) & 1u)) >> 16;
    ub = (ub + 0x7fffu + ((ub >> 16) & 1u)) & 0xffff0000u;
    return ua | ub;
}
__device__ __forceinline__ float bf_lo(unsigned u) { return __uint_as_float(u << 16); }
__device__ __forceinline__ float bf_hi(unsigned u) { return __uint_as_float(u & 0xffff0000u); }

// R12: REPLICATED PUBLISH (fan-out test). Ledger: R9 (512x less poll volume)
// flat; R10 (coalesced publish, WRITE 557->164 MB) flat; R11 (3-deep poll)
// = -48 persistent VGPRs over the 128-reg cap -> SCRATCH SPILL of the sweep
// buffers (FETCH 88.6 GB = spill traffic, VALUBusy 5.6%) -- register-
// infeasible, reverted. Remaining untested traffic mechanism: per-line
// consumer FAN-OUT. Every h line is polled by 256 WGs; the L3 serves one
// request per line at a time, so the LAST consumer's discovery carries the
// serialization tail, and the step advances at the slowest consumer's pace.
// Now: producers store h to 8 replicas (stores proven free by R10);
// consumer WG polls replica wg&7 -> fan-out 256 -> 32. Poll loop, backoff,
// and register footprint are byte-identical to R8 (best: 18.07 ms).
// Kept from R11 (innocent, LDS-only): x prefetched 2 steps ahead so the
// fresh-from-HBM x line never pokes into the serial chain.
// Gen-parity safety unchanged: buf[t&1] only ever holds gens t, t+2, ...;
// '== t' polling can never miss or skip a generation.
__global__ __launch_bounds__(512, 2) void snn_persistent(
    const float* __restrict__ x, const float* __restrict__ Win,
    const float* __restrict__ Wrec, const float* __restrict__ Wout,
    const float* __restrict__ gbias, float* __restrict__ y,
    u64* __restrict__ hbuf)
{
    __shared__ __attribute__((aligned(16))) float h_lds[H_DIM];   // 16 KB
    __shared__ __attribute__((aligned(16))) float xb0[IN_DIM];    // 4 KB
    __shared__ __attribute__((aligned(16))) float xb1[IN_DIM];    // 4 KB
    __shared__ float osc[8][2];

    const int tid = threadIdx.x;
    const int w   = tid >> 6;     // wave 0..7
    const int l   = tid & 63;     // lane
    const int wg  = blockIdx.x;   // 0..255

    const int rowA  = wg * 16 + w;      // both W_rec rows register-resident
    const int rowB  = rowA + 8;
    const int orow0 = wg * 2;
    const int orow1 = orow0 + 1;
    const int repoff = (wg & (N_REP - 1)) << 12;  // this WG's poll replica

    // ---- one-time: 32 register-resident W_rec row-slices (128 VGPRs) ----
    const float4* pa = (const float4*)Wrec + (size_t)rowA * (H_DIM / 4) + l;
    const float4* pb = (const float4*)Wrec + (size_t)rowB * (H_DIM / 4) + l;
#define WRL(k) float4 wa##k = pa[(k) * 64]; PIN4(wa##k); \
               float4 wb##k = pb[(k) * 64]; PIN4(wb##k);
    WRL(0) WRL(1) WRL(2) WRL(3) WRL(4) WRL(5) WRL(6) WRL(7)
    WRL(8) WRL(9) WRL(10) WRL(11) WRL(12) WRL(13) WRL(14) WRL(15)
#undef WRL

    const float4* pia = (const float4*)Win + (size_t)rowA * (IN_DIM / 4) + l;
    const float4* pib = (const float4*)Win + (size_t)rowB * (IN_DIM / 4) + l;
    unsigned wiA[8], wiB[8];
    #pragma unroll
    for (int k = 0; k < 4; ++k) {
        float4 va = pia[k * 64], vb = pib[k * 64];
        wiA[2 * k]     = pack_bf2(va.x, va.y);
        wiA[2 * k + 1] = pack_bf2(va.z, va.w);
        wiB[2 * k]     = pack_bf2(vb.x, vb.y);
        wiB[2 * k + 1] = pack_bf2(vb.z, vb.w);
    }

    const float* po0 = Wout + (size_t)orow0 * H_DIM + tid;
    const float* po1 = Wout + (size_t)orow1 * H_DIM + tid;
    unsigned woP0[4], woP1[4];
    #pragma unroll
    for (int j = 0; j < 4; ++j) {
        woP0[j] = pack_bf2(po0[1024 * j], po0[1024 * j + 512]);
        woP1[j] = pack_bf2(po1[1024 * j], po1[1024 * j + 512]);
    }

    const float gbA  = gbias[rowA];
    const float gbB  = gbias[rowB];
    const float leak = 0.1f;

    // hbuf layout: [parity][replica][H_DIM] u64.
    u64* B0 = hbuf;                   // gens t even (memset 0 => gen0, h0=0)
    u64* B1 = hbuf + N_REP * H_DIM;   // gens t odd

    float iA, iB;            // input currents, computed one step ahead
#define COMPUTE_I(XB) do { iA = 0.f; iB = 0.f;                                  \
        const float4* x4_ = (const float4*)(XB);                                \
        _Pragma("unroll")                                                       \
        for (int k = 0; k < 4; ++k) {                                           \
            float4 xv = x4_[k * 64 + l];                                        \
            unsigned a0 = wiA[2 * k], a1 = wiA[2 * k + 1];                      \
            unsigned c0 = wiB[2 * k], c1 = wiB[2 * k + 1];                      \
            iA = fmaf(bf_lo(a0), xv.x, fmaf(bf_hi(a0), xv.y,                    \
                 fmaf(bf_lo(a1), xv.z, fmaf(bf_hi(a1), xv.w, iA))));            \
            iB = fmaf(bf_lo(c0), xv.x, fmaf(bf_hi(c0), xv.y,                    \
                 fmaf(bf_lo(c1), xv.z, fmaf(bf_hi(c1), xv.w, iB))));            \
        }                                                                       \
        _Pragma("unroll")                                                       \
        for (int off = 32; off; off >>= 1) {                                    \
            iA += __shfl_xor(iA, off); iB += __shfl_xor(iB, off);               \
        } } while (0)

    float vals[8];           // this thread's 8 freshly-polled h values
    // R8-identical masked sweep, but against this WG's replica only.
#define POLL_STAGE(SRCB, GEN) do { unsigned pend = 0xffu;                       \
        while (pend) {                                                          \
            _Pragma("unroll")                                                   \
            for (int k = 0; k < 8; ++k) if (pend & (1u << k)) {                 \
                u64 v_ = __hip_atomic_load(&(SRCB)[repoff + tid + (k << 9)],    \
                        __ATOMIC_RELAXED, __HIP_MEMORY_SCOPE_AGENT);            \
                if ((unsigned)(v_ >> 32) == (GEN)) {                            \
                    vals[k] = __uint_as_float((unsigned)v_);                    \
                    pend &= ~(1u << k);                                         \
                }                                                               \
            }                                                                   \
            if (pend) __builtin_amdgcn_s_sleep(1);  /* ~64cy backoff */         \
        } } while (0)

    // W_out partials straight from vals[] registers (slot k = tid + 512k, so
    // vals[2j]/vals[2j+1] are exactly h[tid+1024j]/h[tid+1024j+512]).
#define WOUT_OSC() do { float p0 = 0.f, p1 = 0.f;                               \
        _Pragma("unroll")                                                       \
        for (int j = 0; j < 4; ++j) {                                           \
            p0 = fmaf(bf_lo(woP0[j]), vals[2 * j],                              \
                 fmaf(bf_hi(woP0[j]), vals[2 * j + 1], p0));                    \
            p1 = fmaf(bf_lo(woP1[j]), vals[2 * j],                              \
                 fmaf(bf_hi(woP1[j]), vals[2 * j + 1], p1));                    \
        }                                                                       \
        _Pragma("unroll")                                                       \
        for (int off = 32; off; off >>= 1) {                                    \
            p0 += __shfl_xor(p0, off); p1 += __shfl_xor(p1, off);               \
        }                                                                       \
        if (l == 0) { osc[w][0] = p0; osc[w][1] = p1; } } while (0)

    // ---- prologue: x_0,x_1 staged (2-ahead pipeline), I(t=0) ----
    if (tid < 256) {
        ((float4*)xb0)[tid] = ((const float4*)x)[tid];
        ((float4*)xb1)[tid] = ((const float4*)(x + IN_DIM))[tid];
    }
    __syncthreads();
    COMPUTE_I(xb0);

    #pragma unroll 1
    for (int t = 0; t < T_STEPS; ++t) {
        const u64* srcb = (t & 1) ? B1 : B0;
        u64*       dstb = (t & 1) ? B0 : B1;

        // ---- the poll IS the grid barrier AND the h staging load ----
        POLL_STAGE(srcb, (unsigned)t);
        #pragma unroll
        for (int k = 0; k < 8; ++k) h_lds[tid + (k << 9)] = vals[k];
        __syncthreads();                          // S1: h_t fully staged

        // ---- CRITICAL PATH: W_rec . h -> reduce -> nonlinearity -> publish
        float4 a = make_float4(0.f, 0.f, 0.f, 0.f);
        float4 b = make_float4(0.f, 0.f, 0.f, 0.f);
        {
            const float4* h4 = (const float4*)h_lds;
#define WRF(k) { float4 hv = h4[(k) * 64 + l];                                  \
                 a.x = fmaf(wa##k.x, hv.x, a.x); a.y = fmaf(wa##k.y, hv.y, a.y);\
                 a.z = fmaf(wa##k.z, hv.z, a.z); a.w = fmaf(wa##k.w, hv.w, a.w);\
                 b.x = fmaf(wb##k.x, hv.x, b.x); b.y = fmaf(wb##k.y, hv.y, b.y);\
                 b.z = fmaf(wb##k.z, hv.z, b.z); b.w = fmaf(wb##k.w, hv.w, b.w); }
            WRF(0) WRF(1) WRF(2) WRF(3) WRF(4) WRF(5) WRF(6) WRF(7)
            WRF(8) WRF(9) WRF(10) WRF(11) WRF(12) WRF(13) WRF(14) WRF(15)
#undef WRF
        }
        float rA = (a.x + a.y) + (a.z + a.w);
        float rB = (b.x + b.y) + (b.z + b.w);
        #pragma unroll
        for (int off = 32; off; off >>= 1) {
            rA += __shfl_xor(rA, off);
            rB += __shfl_xor(rB, off);
        }
        if (l == 0) {                             // immediate 8-replica publish
            float gA = sigmoid_f(gbA + rA);
            float zA = tanh_f(fmaf(gA, rA, iA));
            float hA = h_lds[rowA];
            u64 pv = ((u64)(unsigned)(t + 1) << 32) |
                     (u64)__float_as_uint(fmaf(leak, zA - hA, hA));
            #pragma unroll
            for (int rp = 0; rp < N_REP; ++rp)
                __hip_atomic_store(&dstb[(rp << 12) + rowA], pv,
                                   __ATOMIC_RELAXED, __HIP_MEMORY_SCOPE_AGENT);
        } else if (l == 1) {
            float gB = sigmoid_f(gbB + rB);
            float zB = tanh_f(fmaf(gB, rB, iB));
            float hB = h_lds[rowB];
            u64 pv = ((u64)(unsigned)(t + 1) << 32) |
                     (u64)__float_as_uint(fmaf(leak, zB - hB, hB));
            #pragma unroll
            for (int rp = 0; rp < N_REP; ++rp)
                __hip_atomic_store(&dstb[(rp << 12) + rowB], pv,
                                   __ATOMIC_RELAXED, __HIP_MEMORY_SCOPE_AGENT);
        }

        // ---- SLACK (h' in flight): x two-ahead, W_out partials, y, W_in ----
        if (t + 2 < T_STEPS && tid < 256) {
            float* xbn = (t & 1) ? xb1 : xb0;     // buffer for x_{t+2}
            ((float4*)xbn)[tid] =
                ((const float4*)(x + (size_t)(t + 2) * IN_DIM))[tid];
        }
        if (t >= 1) WOUT_OSC();                   // y_{t-1} partials from vals
        __syncthreads();                          // S2: osc + x buffers ready
        if (t >= 1 && tid == 0) {
            float s0 = 0.f, s1 = 0.f;
            #pragma unroll
            for (int q = 0; q < 8; ++q) { s0 += osc[q][0]; s1 += osc[q][1]; }
            y[(size_t)(t - 1) * O_DIM + orow0] = s0;
            y[(size_t)(t - 1) * O_DIM + orow1] = s1;
        }
        if (t + 1 < T_STEPS) {                    // I for t+1 from x_{t+1}
            const float* xbc = (t & 1) ? xb0 : xb1;
            COMPUTE_I(xbc);
        }
    }

    // ---- epilogue: y[T-1] = W_out . h_T (gen T sits in B0, T even) ----
    POLL_STAGE(B0, (unsigned)T_STEPS);
    __syncthreads();   // ensure tid0 finished reading osc for y[T-2]
    WOUT_OSC();
    __syncthreads();
    if (tid == 0) {
        float s0 = 0.f, s1 = 0.f;
        #pragma unroll
        for (int q = 0; q < 8; ++q) { s0 += osc[q][0]; s1 += osc[q][1]; }
        y[(size_t)(T_STEPS - 1) * O_DIM + orow0] = s0;
        y[(size_t)(T_STEPS - 1) * O_DIM + orow1] = s1;
    }
}

extern "C" void kernel_launch(void* const* d_in, const int* in_sizes, int n_in,
                              void* d_out, int out_size, void* d_ws, size_t ws_size,
                              hipStream_t stream) {
    const float* x     = (const float*)d_in[0];
    const float* Win   = (const float*)d_in[1];
    const float* Wrec  = (const float*)d_in[2];
    const float* Wout  = (const float*)d_in[3];
    const float* gbias = (const float*)d_in[4];
    float* y = (float*)d_out;

    u64* hbuf = (u64*)d_ws;  // [2][N_REP][H_DIM] gen-tagged u64 = 512 KB

    // ws is re-poisoned before every replay: zero => h0 = 0 with gen 0.
    hipMemsetAsync(d_ws, 0, (size_t)2 * N_REP * H_DIM * sizeof(u64), stream);

    void* args[] = { (void*)&x, (void*)&Win, (void*)&Wrec, (void*)&Wout,
                     (void*)&gbias, (void*)&y, (void*)&hbuf };
    hipLaunchCooperativeKernel((const void*)snn_persistent, dim3(N_WG), dim3(512),
                               args, 0, stream);
}

// Round 7
// 14069.080 us; speedup vs baseline: 6.4289x; 1.3883x over previous
//
#include <hip/hip_runtime.h>
#include <cstddef>

#define T_STEPS 4096
#define H_DIM   4096
#define IN_DIM  1024
#define O_DIM   512
#define N_WG    256   // 1 block/CU -- launch shape proven in prior rounds

typedef unsigned long long u64;

__device__ __forceinline__ float sigmoid_f(float v) {
    v = fminf(fmaxf(v, -30.f), 30.f);
    return 1.f / (1.f + __expf(-v));
}
__device__ __forceinline__ float tanh_f(float v) {
    v = fminf(fmaxf(v, -15.f), 15.f);
    float e = __expf(2.f * v);
    return (e - 1.f) / (e + 1.f);
}

// Keep W_rec register rows opaque so the scheduler can't sink/remat the
// global loads into the t-loop (prior rounds: remat = 84 MB/step L2 re-reads).
#define PIN4(v) asm volatile("" : "+v"(v.x), "+v"(v.y), "+v"(v.z), "+v"(v.w))

// fp32 -> packed bf16x2 (round-to-nearest-even), and unpack helpers.
__device__ __forceinline__ unsigned pack_bf2(float a, float b) {
    unsigned ua = __float_as_uint(a), ub = __float_as_uint(b);
    ua = (ua + 0x7fffu + ((ua >> 16) & 1u)) >> 16;
    ub = (ub + 0x7fffu + ((ub >> 16) & 1u)) & 0xffff0000u;
    return ua | ub;
}
__device__ __forceinline__ float bf_lo(unsigned u) { return __uint_as_float(u << 16); }
__device__ __forceinline__ float bf_hi(unsigned u) { return __uint_as_float(u & 0xffff0000u); }

// R13: TAG-IN-MANTISSA EXCHANGE (protocol width halved). Ledger: R9 (poll
// volume -512x) flat, R10 (coalesced publish) flat, R11 (pipelined poll)
// register-infeasible, R12 (8x replicas, fan-out 256->32) flat. All
// contention axes falsified AT FIXED PROTOCOL WIDTH. R9's flat result is
// ambiguous on the bandwidth axis (it traded sweep BW for +1 serial RT).
// This round bisects: h words shrink u64 -> u32 with the gen tag in the
// LOW 2 MANTISSA BITS (word = h_bits&~3 | gen&3). WG skew is provably <=2
// gens, so 2 bits distinguish all reachable states (t vs t-2 mod 4).
// Precision cost 2^-22/step, leak-damped to ~1e-6 total. Sweep bytes halve
// (8->4 MB grid-wide), per-thread poll transactions halve (8 u64 -> 4 u64,
// each covering 2 adjacent tagged rows). Poll structure/backoff/registers
// byte-identical to R8 (best: 18.07 ms). BW-bound => ~13-15 ms; flat =>
// latency floor proven, roofline next.
__global__ __launch_bounds__(512, 2) void snn_persistent(
    const float* __restrict__ x, const float* __restrict__ Win,
    const float* __restrict__ Wrec, const float* __restrict__ Wout,
    const float* __restrict__ gbias, float* __restrict__ y,
    unsigned* __restrict__ hbuf)
{
    __shared__ __attribute__((aligned(16))) float h_lds[H_DIM];   // 16 KB
    __shared__ __attribute__((aligned(16))) float xb0[IN_DIM];    // 4 KB
    __shared__ __attribute__((aligned(16))) float xb1[IN_DIM];    // 4 KB
    __shared__ float osc[8][2];

    const int tid = threadIdx.x;
    const int w   = tid >> 6;     // wave 0..7
    const int l   = tid & 63;     // lane
    const int wg  = blockIdx.x;   // 0..255

    const int rowA  = wg * 16 + w;      // both W_rec rows register-resident
    const int rowB  = rowA + 8;
    const int orow0 = wg * 2;
    const int orow1 = orow0 + 1;

    // ---- one-time: 32 register-resident W_rec row-slices (128 VGPRs) ----
    const float4* pa = (const float4*)Wrec + (size_t)rowA * (H_DIM / 4) + l;
    const float4* pb = (const float4*)Wrec + (size_t)rowB * (H_DIM / 4) + l;
#define WRL(k) float4 wa##k = pa[(k) * 64]; PIN4(wa##k); \
               float4 wb##k = pb[(k) * 64]; PIN4(wb##k);
    WRL(0) WRL(1) WRL(2) WRL(3) WRL(4) WRL(5) WRL(6) WRL(7)
    WRL(8) WRL(9) WRL(10) WRL(11) WRL(12) WRL(13) WRL(14) WRL(15)
#undef WRL

    const float4* pia = (const float4*)Win + (size_t)rowA * (IN_DIM / 4) + l;
    const float4* pib = (const float4*)Win + (size_t)rowB * (IN_DIM / 4) + l;
    unsigned wiA[8], wiB[8];
    #pragma unroll
    for (int k = 0; k < 4; ++k) {
        float4 va = pia[k * 64], vb = pib[k * 64];
        wiA[2 * k]     = pack_bf2(va.x, va.y);
        wiA[2 * k + 1] = pack_bf2(va.z, va.w);
        wiB[2 * k]     = pack_bf2(vb.x, vb.y);
        wiB[2 * k + 1] = pack_bf2(vb.z, vb.w);
    }

    // W_out taps for the new pair layout: thread owns rows {2tid, 2tid+1}
    // + 1024k, k=0..3 (matching the u64 poll slots below).
    const float* po0b = Wout + (size_t)orow0 * H_DIM + 2 * tid;
    const float* po1b = Wout + (size_t)orow1 * H_DIM + 2 * tid;
    unsigned woP0[4], woP1[4];
    #pragma unroll
    for (int j = 0; j < 4; ++j) {
        woP0[j] = pack_bf2(po0b[1024 * j], po0b[1024 * j + 1]);
        woP1[j] = pack_bf2(po1b[1024 * j], po1b[1024 * j + 1]);
    }

    const float gbA  = gbias[rowA];
    const float gbB  = gbias[rowB];
    const float leak = 0.1f;

    // hbuf: [parity][H_DIM] u32, tag = low 2 bits (memset 0 => gen0, h0=0).
    unsigned* h32_0 = hbuf;           // even gens
    unsigned* h32_1 = hbuf + H_DIM;   // odd gens
    const u64* b0 = (const u64*)h32_0;  // u64 view: slot = 2 adjacent rows
    const u64* b1 = (const u64*)h32_1;

    float iA, iB;            // input currents, computed one step ahead
#define COMPUTE_I(XB) do { iA = 0.f; iB = 0.f;                                  \
        const float4* x4_ = (const float4*)(XB);                                \
        _Pragma("unroll")                                                       \
        for (int k = 0; k < 4; ++k) {                                           \
            float4 xv = x4_[k * 64 + l];                                        \
            unsigned a0 = wiA[2 * k], a1 = wiA[2 * k + 1];                      \
            unsigned c0 = wiB[2 * k], c1 = wiB[2 * k + 1];                      \
            iA = fmaf(bf_lo(a0), xv.x, fmaf(bf_hi(a0), xv.y,                    \
                 fmaf(bf_lo(a1), xv.z, fmaf(bf_hi(a1), xv.w, iA))));            \
            iB = fmaf(bf_lo(c0), xv.x, fmaf(bf_hi(c0), xv.y,                    \
                 fmaf(bf_lo(c1), xv.z, fmaf(bf_hi(c1), xv.w, iB))));            \
        }                                                                       \
        _Pragma("unroll")                                                       \
        for (int off = 32; off; off >>= 1) {                                    \
            iA += __shfl_xor(iA, off); iB += __shfl_xor(iB, off);               \
        } } while (0)

    float vlo[4], vhi[4];    // this thread's 8 freshly-polled h values
    // R8-identical masked sweep, half-width: 4 u64 slots, accept when BOTH
    // u32 halves carry tag (gen&3).
#define POLL_STAGE(SRC, GEN) do { unsigned pend = 0xfu;                         \
        const unsigned tag_ = (unsigned)(GEN) & 3u;                             \
        while (pend) {                                                          \
            _Pragma("unroll")                                                   \
            for (int k = 0; k < 4; ++k) if (pend & (1u << k)) {                 \
                u64 v_ = __hip_atomic_load(&(SRC)[tid + (k << 9)],              \
                        __ATOMIC_RELAXED, __HIP_MEMORY_SCOPE_AGENT);            \
                unsigned lo_ = (unsigned)v_, hi_ = (unsigned)(v_ >> 32);        \
                if (((lo_ & 3u) == tag_) && ((hi_ & 3u) == tag_)) {             \
                    vlo[k] = __uint_as_float(lo_);                              \
                    vhi[k] = __uint_as_float(hi_);                              \
                    pend &= ~(1u << k);                                         \
                }                                                               \
            }                                                                   \
            if (pend) __builtin_amdgcn_s_sleep(1);  /* ~64cy backoff */         \
        } } while (0)

    // W_out partials straight from vlo/vhi (slot k = rows 2tid/2tid+1+1024k).
#define WOUT_OSC() do { float p0 = 0.f, p1 = 0.f;                               \
        _Pragma("unroll")                                                       \
        for (int j = 0; j < 4; ++j) {                                           \
            p0 = fmaf(bf_lo(woP0[j]), vlo[j],                                   \
                 fmaf(bf_hi(woP0[j]), vhi[j], p0));                             \
            p1 = fmaf(bf_lo(woP1[j]), vlo[j],                                   \
                 fmaf(bf_hi(woP1[j]), vhi[j], p1));                             \
        }                                                                       \
        _Pragma("unroll")                                                       \
        for (int off = 32; off; off >>= 1) {                                    \
            p0 += __shfl_xor(p0, off); p1 += __shfl_xor(p1, off);               \
        }                                                                       \
        if (l == 0) { osc[w][0] = p0; osc[w][1] = p1; } } while (0)

    // ---- prologue: x_0,x_1 staged (2-ahead pipeline), I(t=0) ----
    if (tid < 256) {
        ((float4*)xb0)[tid] = ((const float4*)x)[tid];
        ((float4*)xb1)[tid] = ((const float4*)(x + IN_DIM))[tid];
    }
    __syncthreads();
    COMPUTE_I(xb0);

    #pragma unroll 1
    for (int t = 0; t < T_STEPS; ++t) {
        const u64* src = (t & 1) ? b1 : b0;
        unsigned*  d32 = (t & 1) ? h32_0 : h32_1;   // gen t+1's buffer

        // ---- the poll IS the grid barrier AND the h staging load ----
        POLL_STAGE(src, (unsigned)t);
        #pragma unroll
        for (int k = 0; k < 4; ++k)
            ((float2*)h_lds)[tid + (k << 9)] = make_float2(vlo[k], vhi[k]);
        __syncthreads();                          // S1: h_t fully staged

        // ---- CRITICAL PATH: W_rec . h -> reduce -> nonlinearity -> publish
        float4 a = make_float4(0.f, 0.f, 0.f, 0.f);
        float4 b = make_float4(0.f, 0.f, 0.f, 0.f);
        {
            const float4* h4 = (const float4*)h_lds;
#define WRF(k) { float4 hv = h4[(k) * 64 + l];                                  \
                 a.x = fmaf(wa##k.x, hv.x, a.x); a.y = fmaf(wa##k.y, hv.y, a.y);\
                 a.z = fmaf(wa##k.z, hv.z, a.z); a.w = fmaf(wa##k.w, hv.w, a.w);\
                 b.x = fmaf(wb##k.x, hv.x, b.x); b.y = fmaf(wb##k.y, hv.y, b.y);\
                 b.z = fmaf(wb##k.z, hv.z, b.z); b.w = fmaf(wb##k.w, hv.w, b.w); }
            WRF(0) WRF(1) WRF(2) WRF(3) WRF(4) WRF(5) WRF(6) WRF(7)
            WRF(8) WRF(9) WRF(10) WRF(11) WRF(12) WRF(13) WRF(14) WRF(15)
#undef WRF
        }
        float rA = (a.x + a.y) + (a.z + a.w);
        float rB = (b.x + b.y) + (b.z + b.w);
        #pragma unroll
        for (int off = 32; off; off >>= 1) {
            rA += __shfl_xor(rA, off);
            rB += __shfl_xor(rB, off);
        }
        const unsigned tagn = (unsigned)(t + 1) & 3u;
        if (l == 0) {                             // immediate tagged publish
            float gA = sigmoid_f(gbA + rA);
            float zA = tanh_f(fmaf(gA, rA, iA));
            float hA = h_lds[rowA];
            unsigned hv = (__float_as_uint(fmaf(leak, zA - hA, hA)) & ~3u) | tagn;
            __hip_atomic_store(&d32[rowA], hv,
                               __ATOMIC_RELAXED, __HIP_MEMORY_SCOPE_AGENT);
        } else if (l == 1) {
            float gB = sigmoid_f(gbB + rB);
            float zB = tanh_f(fmaf(gB, rB, iB));
            float hB = h_lds[rowB];
            unsigned hv = (__float_as_uint(fmaf(leak, zB - hB, hB)) & ~3u) | tagn;
            __hip_atomic_store(&d32[rowB], hv,
                               __ATOMIC_RELAXED, __HIP_MEMORY_SCOPE_AGENT);
        }

        // ---- SLACK (h' in flight): x two-ahead, W_out partials, y, W_in ----
        if (t + 2 < T_STEPS && tid < 256) {
            float* xbn = (t & 1) ? xb1 : xb0;     // buffer for x_{t+2}
            ((float4*)xbn)[tid] =
                ((const float4*)(x + (size_t)(t + 2) * IN_DIM))[tid];
        }
        if (t >= 1) WOUT_OSC();                   // y_{t-1} partials
        __syncthreads();                          // S2: osc + x buffers ready
        if (t >= 1 && tid == 0) {
            float s0 = 0.f, s1 = 0.f;
            #pragma unroll
            for (int q = 0; q < 8; ++q) { s0 += osc[q][0]; s1 += osc[q][1]; }
            y[(size_t)(t - 1) * O_DIM + orow0] = s0;
            y[(size_t)(t - 1) * O_DIM + orow1] = s1;
        }
        if (t + 1 < T_STEPS) {                    // I for t+1 from x_{t+1}
            const float* xbc = (t & 1) ? xb0 : xb1;
            COMPUTE_I(xbc);
        }
    }

    // ---- epilogue: y[T-1] = W_out . h_T (gen T sits in b0, T even) ----
    POLL_STAGE(b0, (unsigned)T_STEPS);
    __syncthreads();   // ensure tid0 finished reading osc for y[T-2]
    WOUT_OSC();
    __syncthreads();
    if (tid == 0) {
        float s0 = 0.f, s1 = 0.f;
        #pragma unroll
        for (int q = 0; q < 8; ++q) { s0 += osc[q][0]; s1 += osc[q][1]; }
        y[(size_t)(T_STEPS - 1) * O_DIM + orow0] = s0;
        y[(size_t)(T_STEPS - 1) * O_DIM + orow1] = s1;
    }
}

extern "C" void kernel_launch(void* const* d_in, const int* in_sizes, int n_in,
                              void* d_out, int out_size, void* d_ws, size_t ws_size,
                              hipStream_t stream) {
    const float* x     = (const float*)d_in[0];
    const float* Win   = (const float*)d_in[1];
    const float* Wrec  = (const float*)d_in[2];
    const float* Wout  = (const float*)d_in[3];
    const float* gbias = (const float*)d_in[4];
    float* y = (float*)d_out;

    unsigned* hbuf = (unsigned*)d_ws;  // [2][H_DIM] tagged u32 = 32 KB

    // ws is re-poisoned before every replay: zero => h0 = 0 with tag 0.
    hipMemsetAsync(d_ws, 0, 2 * H_DIM * sizeof(unsigned), stream);

    void* args[] = { (void*)&x, (void*)&Win, (void*)&Wrec, (void*)&Wout,
                     (void*)&gbias, (void*)&y, (void*)&hbuf };
    hipLaunchCooperativeKernel((const void*)snn_persistent, dim3(N_WG), dim3(512),
                               args, 0, stream);
}

// Round 9
// 11349.515 us; speedup vs baseline: 7.9694x; 1.2396x over previous
//
#include <hip/hip_runtime.h>
#include <cstddef>

#define T_STEPS 4096
#define H_DIM   4096
#define IN_DIM  1024
#define O_DIM   512
#define N_WG    256   // 1 block/CU -- launch shape proven in prior rounds

typedef unsigned long long u64;

__device__ __forceinline__ float sigmoid_f(float v) {
    v = fminf(fmaxf(v, -30.f), 30.f);
    return 1.f / (1.f + __expf(-v));
}
__device__ __forceinline__ float tanh_f(float v) {
    v = fminf(fmaxf(v, -15.f), 15.f);
    float e = __expf(2.f * v);
    return (e - 1.f) / (e + 1.f);
}

// Keep W_rec register rows opaque so the scheduler can't sink/remat the
// global loads into the t-loop (prior rounds: remat = 84 MB/step L2 re-reads).
#define PIN4(v) asm volatile("" : "+v"(v.x), "+v"(v.y), "+v"(v.z), "+v"(v.w))

// fp32 -> packed bf16x2 (round-to-nearest-even), and unpack helpers.
__device__ __forceinline__ unsigned pack_bf2(float a, float b) {
    unsigned ua = __float_as_uint(a), ub = __float_as_uint(b);
    ua = (ua + 0x7fffu + ((ua >> 16) & 1u)) >> 16;
    ub = (ub + 0x7fffu + ((ub >> 16) & 1u)) & 0xffff0000u;
    return ua | ub;
}
__device__ __forceinline__ float bf_lo(unsigned u) { return __uint_as_float(u << 16); }
__device__ __forceinline__ float bf_hi(unsigned u) { return __uint_as_float(u & 0xffff0000u); }

// R14 (resubmit -- R8's bench was the same infra-failure signature as R3,
// which ran clean on identical resubmission; asm audited: sc0/sc1 spelling,
// 128-bit "v" tuples, coverage/termination, alignment all sound).
// 16-BYTE POLL GRANULES. R13 (u64->u32 tagged words) gave -22% and FETCH
// dropped 635->373 MB: the exchange is TRANSACTION/WIDTH-limited at the
// coherence point -- sweep period scales with aggregate L3 service of the
// poll flood. Tag-in-mantissa made the atomicity unit 4 B, so polling
// needs no atomic loads: one global_load_dwordx4 sc0 sc1 (system scope =
// bypasses L1 + non-coherent XCD L2, safe superset of AGENT atomic-load)
// fetches 4 tagged rows per transaction. Per-thread sweep transactions
// 4 -> 2 (grid-wide 0.5M -> 0.26M per sweep), same bytes. Publish, backoff,
// barriers, gen-parity safety, x 2-ahead prefetch: identical to R13.
// Skew proof unchanged: gens present in buf[t&1] are only {t-2, t}; tags
// (gen&3) differ by 2 mod 4 => '==tag' acceptance can't miss or skip.
__global__ __launch_bounds__(512, 2) void snn_persistent(
    const float* __restrict__ x, const float* __restrict__ Win,
    const float* __restrict__ Wrec, const float* __restrict__ Wout,
    const float* __restrict__ gbias, float* __restrict__ y,
    unsigned* __restrict__ hbuf)
{
    __shared__ __attribute__((aligned(16))) float h_lds[H_DIM];   // 16 KB
    __shared__ __attribute__((aligned(16))) float xb0[IN_DIM];    // 4 KB
    __shared__ __attribute__((aligned(16))) float xb1[IN_DIM];    // 4 KB
    __shared__ float osc[8][2];

    const int tid = threadIdx.x;
    const int w   = tid >> 6;     // wave 0..7
    const int l   = tid & 63;     // lane
    const int wg  = blockIdx.x;   // 0..255

    const int rowA  = wg * 16 + w;      // both W_rec rows register-resident
    const int rowB  = rowA + 8;
    const int orow0 = wg * 2;
    const int orow1 = orow0 + 1;

    // ---- one-time: 32 register-resident W_rec row-slices (128 VGPRs) ----
    const float4* pa = (const float4*)Wrec + (size_t)rowA * (H_DIM / 4) + l;
    const float4* pb = (const float4*)Wrec + (size_t)rowB * (H_DIM / 4) + l;
#define WRL(k) float4 wa##k = pa[(k) * 64]; PIN4(wa##k); \
               float4 wb##k = pb[(k) * 64]; PIN4(wb##k);
    WRL(0) WRL(1) WRL(2) WRL(3) WRL(4) WRL(5) WRL(6) WRL(7)
    WRL(8) WRL(9) WRL(10) WRL(11) WRL(12) WRL(13) WRL(14) WRL(15)
#undef WRL

    const float4* pia = (const float4*)Win + (size_t)rowA * (IN_DIM / 4) + l;
    const float4* pib = (const float4*)Win + (size_t)rowB * (IN_DIM / 4) + l;
    unsigned wiA[8], wiB[8];
    #pragma unroll
    for (int k = 0; k < 4; ++k) {
        float4 va = pia[k * 64], vb = pib[k * 64];
        wiA[2 * k]     = pack_bf2(va.x, va.y);
        wiA[2 * k + 1] = pack_bf2(va.z, va.w);
        wiB[2 * k]     = pack_bf2(vb.x, vb.y);
        wiB[2 * k + 1] = pack_bf2(vb.z, vb.w);
    }

    // W_out taps for the granule layout: thread owns rows 4tid+2048g+j,
    // g=0..1, j=0..3 (matching the dwordx4 poll granules below).
    const float* po0b = Wout + (size_t)orow0 * H_DIM + 4 * tid;
    const float* po1b = Wout + (size_t)orow1 * H_DIM + 4 * tid;
    unsigned woP0[4], woP1[4];
    #pragma unroll
    for (int g = 0; g < 2; ++g)
        #pragma unroll
        for (int m = 0; m < 2; ++m) {
            woP0[2 * g + m] = pack_bf2(po0b[2048 * g + 2 * m],
                                       po0b[2048 * g + 2 * m + 1]);
            woP1[2 * g + m] = pack_bf2(po1b[2048 * g + 2 * m],
                                       po1b[2048 * g + 2 * m + 1]);
        }

    const float gbA  = gbias[rowA];
    const float gbB  = gbias[rowB];
    const float leak = 0.1f;

    // hbuf: [parity][H_DIM] u32, tag = low 2 bits (memset 0 => gen0, h0=0).
    unsigned* h32_0 = hbuf;           // even gens
    unsigned* h32_1 = hbuf + H_DIM;   // odd gens

    float iA, iB;            // input currents, computed one step ahead
#define COMPUTE_I(XB) do { iA = 0.f; iB = 0.f;                                  \
        const float4* x4_ = (const float4*)(XB);                                \
        _Pragma("unroll")                                                       \
        for (int k = 0; k < 4; ++k) {                                           \
            float4 xv = x4_[k * 64 + l];                                        \
            unsigned a0 = wiA[2 * k], a1 = wiA[2 * k + 1];                      \
            unsigned c0 = wiB[2 * k], c1 = wiB[2 * k + 1];                      \
            iA = fmaf(bf_lo(a0), xv.x, fmaf(bf_hi(a0), xv.y,                    \
                 fmaf(bf_lo(a1), xv.z, fmaf(bf_hi(a1), xv.w, iA))));            \
            iB = fmaf(bf_lo(c0), xv.x, fmaf(bf_hi(c0), xv.y,                    \
                 fmaf(bf_lo(c1), xv.z, fmaf(bf_hi(c1), xv.w, iB))));            \
        }                                                                       \
        _Pragma("unroll")                                                       \
        for (int off = 32; off; off >>= 1) {                                    \
            iA += __shfl_xor(iA, off); iB += __shfl_xor(iB, off);               \
        } } while (0)

    uint4 g0, g1;            // this thread's 2 accepted 4-row granules
    // Masked sweep over 2 16-B granules; per-4B tags make non-atomic vector
    // loads safe. Loads are system-scope (sc0 sc1) to bypass L1 + XCD L2.
#define POLL_STAGE(SRC32, GEN) do { unsigned pend = 0x3u;                       \
        const unsigned tag_ = (unsigned)(GEN) & 3u;                             \
        const uint4* s4_ = (const uint4*)(SRC32);                               \
        const uint4* p0_ = s4_ + tid;                                           \
        const uint4* p1_ = s4_ + tid + 512;                                     \
        while (pend) {                                                          \
            uint4 q0_, q1_;                                                     \
            asm volatile(                                                       \
                "global_load_dwordx4 %0, %2, off sc0 sc1\n\t"                   \
                "global_load_dwordx4 %1, %3, off sc0 sc1\n\t"                   \
                "s_waitcnt vmcnt(0)"                                            \
                : "=&v"(q0_), "=&v"(q1_)                                        \
                : "v"(p0_), "v"(p1_)                                            \
                : "memory");                                                    \
            if (pend & 1u) {                                                    \
                unsigned m_ = ((q0_.x ^ tag_) | (q0_.y ^ tag_) |                \
                               (q0_.z ^ tag_) | (q0_.w ^ tag_)) & 3u;           \
                if (m_ == 0u) { g0 = q0_; pend &= ~1u; }                        \
            }                                                                   \
            if (pend & 2u) {                                                    \
                unsigned m_ = ((q1_.x ^ tag_) | (q1_.y ^ tag_) |                \
                               (q1_.z ^ tag_) | (q1_.w ^ tag_)) & 3u;           \
                if (m_ == 0u) { g1 = q1_; pend &= ~2u; }                        \
            }                                                                   \
            if (pend) __builtin_amdgcn_s_sleep(1);  /* ~64cy backoff */         \
        } } while (0)

    // W_out partials straight from granules (g covers rows 4tid+2048g+0..3).
#define WOUT_OSC() do { float p0 = 0.f, p1 = 0.f;                               \
        float v0_[4] = { __uint_as_float(g0.x), __uint_as_float(g0.y),          \
                         __uint_as_float(g0.z), __uint_as_float(g0.w) };        \
        float v1_[4] = { __uint_as_float(g1.x), __uint_as_float(g1.y),          \
                         __uint_as_float(g1.z), __uint_as_float(g1.w) };        \
        _Pragma("unroll")                                                       \
        for (int m = 0; m < 2; ++m) {                                           \
            p0 = fmaf(bf_lo(woP0[m]), v0_[2 * m],                               \
                 fmaf(bf_hi(woP0[m]), v0_[2 * m + 1], p0));                     \
            p0 = fmaf(bf_lo(woP0[2 + m]), v1_[2 * m],                           \
                 fmaf(bf_hi(woP0[2 + m]), v1_[2 * m + 1], p0));                 \
            p1 = fmaf(bf_lo(woP1[m]), v0_[2 * m],                               \
                 fmaf(bf_hi(woP1[m]), v0_[2 * m + 1], p1));                     \
            p1 = fmaf(bf_lo(woP1[2 + m]), v1_[2 * m],                           \
                 fmaf(bf_hi(woP1[2 + m]), v1_[2 * m + 1], p1));                 \
        }                                                                       \
        _Pragma("unroll")                                                       \
        for (int off = 32; off; off >>= 1) {                                    \
            p0 += __shfl_xor(p0, off); p1 += __shfl_xor(p1, off);               \
        }                                                                       \
        if (l == 0) { osc[w][0] = p0; osc[w][1] = p1; } } while (0)

    // ---- prologue: x_0,x_1 staged (2-ahead pipeline), I(t=0) ----
    if (tid < 256) {
        ((float4*)xb0)[tid] = ((const float4*)x)[tid];
        ((float4*)xb1)[tid] = ((const float4*)(x + IN_DIM))[tid];
    }
    __syncthreads();
    COMPUTE_I(xb0);

    #pragma unroll 1
    for (int t = 0; t < T_STEPS; ++t) {
        const unsigned* s32 = (t & 1) ? h32_1 : h32_0;
        unsigned*       d32 = (t & 1) ? h32_0 : h32_1;   // gen t+1's buffer

        // ---- the poll IS the grid barrier AND the h staging load ----
        POLL_STAGE(s32, (unsigned)t);
        ((uint4*)h_lds)[tid]       = g0;   // rows 4tid   .. 4tid+3
        ((uint4*)h_lds)[tid + 512] = g1;   // rows +2048  .. +2051
        __syncthreads();                          // S1: h_t fully staged

        // ---- CRITICAL PATH: W_rec . h -> reduce -> nonlinearity -> publish
        float4 a = make_float4(0.f, 0.f, 0.f, 0.f);
        float4 b = make_float4(0.f, 0.f, 0.f, 0.f);
        {
            const float4* h4 = (const float4*)h_lds;
#define WRF(k) { float4 hv = h4[(k) * 64 + l];                                  \
                 a.x = fmaf(wa##k.x, hv.x, a.x); a.y = fmaf(wa##k.y, hv.y, a.y);\
                 a.z = fmaf(wa##k.z, hv.z, a.z); a.w = fmaf(wa##k.w, hv.w, a.w);\
                 b.x = fmaf(wb##k.x, hv.x, b.x); b.y = fmaf(wb##k.y, hv.y, b.y);\
                 b.z = fmaf(wb##k.z, hv.z, b.z); b.w = fmaf(wb##k.w, hv.w, b.w); }
            WRF(0) WRF(1) WRF(2) WRF(3) WRF(4) WRF(5) WRF(6) WRF(7)
            WRF(8) WRF(9) WRF(10) WRF(11) WRF(12) WRF(13) WRF(14) WRF(15)
#undef WRF
        }
        float rA = (a.x + a.y) + (a.z + a.w);
        float rB = (b.x + b.y) + (b.z + b.w);
        #pragma unroll
        for (int off = 32; off; off >>= 1) {
            rA += __shfl_xor(rA, off);
            rB += __shfl_xor(rB, off);
        }
        const unsigned tagn = (unsigned)(t + 1) & 3u;
        if (l == 0) {                             // immediate tagged publish
            float gA = sigmoid_f(gbA + rA);
            float zA = tanh_f(fmaf(gA, rA, iA));
            float hA = h_lds[rowA];
            unsigned hv = (__float_as_uint(fmaf(leak, zA - hA, hA)) & ~3u) | tagn;
            __hip_atomic_store(&d32[rowA], hv,
                               __ATOMIC_RELAXED, __HIP_MEMORY_SCOPE_AGENT);
        } else if (l == 1) {
            float gB = sigmoid_f(gbB + rB);
            float zB = tanh_f(fmaf(gB, rB, iB));
            float hB = h_lds[rowB];
            unsigned hv = (__float_as_uint(fmaf(leak, zB - hB, hB)) & ~3u) | tagn;
            __hip_atomic_store(&d32[rowB], hv,
                               __ATOMIC_RELAXED, __HIP_MEMORY_SCOPE_AGENT);
        }

        // ---- SLACK (h' in flight): x two-ahead, W_out partials, y, W_in ----
        if (t + 2 < T_STEPS && tid < 256) {
            float* xbn = (t & 1) ? xb1 : xb0;     // buffer for x_{t+2}
            ((float4*)xbn)[tid] =
                ((const float4*)(x + (size_t)(t + 2) * IN_DIM))[tid];
        }
        if (t >= 1) WOUT_OSC();                   // y_{t-1} partials
        __syncthreads();                          // S2: osc + x buffers ready
        if (t >= 1 && tid == 0) {
            float s0 = 0.f, s1 = 0.f;
            #pragma unroll
            for (int q = 0; q < 8; ++q) { s0 += osc[q][0]; s1 += osc[q][1]; }
            y[(size_t)(t - 1) * O_DIM + orow0] = s0;
            y[(size_t)(t - 1) * O_DIM + orow1] = s1;
        }
        if (t + 1 < T_STEPS) {                    // I for t+1 from x_{t+1}
            const float* xbc = (t & 1) ? xb0 : xb1;
            COMPUTE_I(xbc);
        }
    }

    // ---- epilogue: y[T-1] = W_out . h_T (gen T sits in h32_0, T even) ----
    POLL_STAGE(h32_0, (unsigned)T_STEPS);
    __syncthreads();   // ensure tid0 finished reading osc for y[T-2]
    WOUT_OSC();
    __syncthreads();
    if (tid == 0) {
        float s0 = 0.f, s1 = 0.f;
        #pragma unroll
        for (int q = 0; q < 8; ++q) { s0 += osc[q][0]; s1 += osc[q][1]; }
        y[(size_t)(T_STEPS - 1) * O_DIM + orow0] = s0;
        y[(size_t)(T_STEPS - 1) * O_DIM + orow1] = s1;
    }
}

extern "C" void kernel_launch(void* const* d_in, const int* in_sizes, int n_in,
                              void* d_out, int out_size, void* d_ws, size_t ws_size,
                              hipStream_t stream) {
    const float* x     = (const float*)d_in[0];
    const float* Win   = (const float*)d_in[1];
    const float* Wrec  = (const float*)d_in[2];
    const float* Wout  = (const float*)d_in[3];
    const float* gbias = (const float*)d_in[4];
    float* y = (float*)d_out;

    unsigned* hbuf = (unsigned*)d_ws;  // [2][H_DIM] tagged u32 = 32 KB

    // ws is re-poisoned before every replay: zero => h0 = 0 with tag 0.
    hipMemsetAsync(d_ws, 0, 2 * H_DIM * sizeof(unsigned), stream);

    void* args[] = { (void*)&x, (void*)&Win, (void*)&Wrec, (void*)&Wout,
                     (void*)&gbias, (void*)&y, (void*)&hbuf };
    hipLaunchCooperativeKernel((const void*)snn_persistent, dim3(N_WG), dim3(512),
                               args, 0, stream);
}

// Round 12
// 10350.034 us; speedup vs baseline: 8.7390x; 1.0966x over previous
//
#include <hip/hip_runtime.h>
#include <cstddef>

#define T_STEPS 4096
#define H_DIM   4096
#define IN_DIM  1024
#define O_DIM   512
#define N_WG    256   // 1 block/CU -- launch shape proven in prior rounds

typedef unsigned long long u64;

__device__ __forceinline__ float sigmoid_f(float v) {
    v = fminf(fmaxf(v, -30.f), 30.f);
    return 1.f / (1.f + __expf(-v));
}
__device__ __forceinline__ float tanh_f(float v) {
    v = fminf(fmaxf(v, -15.f), 15.f);
    float e = __expf(2.f * v);
    return (e - 1.f) / (e + 1.f);
}

// Keep W_rec register rows opaque so the scheduler can't sink/remat the
// global loads into the t-loop (prior rounds: remat = 84 MB/step L2 re-reads).
#define PIN4(v) asm volatile("" : "+v"(v.x), "+v"(v.y), "+v"(v.z), "+v"(v.w))

// fp32 -> packed bf16x2 (round-to-nearest-even), and unpack helpers.
__device__ __forceinline__ unsigned pack_bf2(float a, float b) {
    unsigned ua = __float_as_uint(a), ub = __float_as_uint(b);
    ua = (ua + 0x7fffu + ((ua >> 16) & 1u)) >> 16;
    ub = (ub + 0x7fffu + ((ub >> 16) & 1u)) & 0xffff0000u;
    return ua | ub;
}
__device__ __forceinline__ float bf_lo(unsigned u) { return __uint_as_float(u << 16); }
__device__ __forceinline__ float bf_hi(unsigned u) { return __uint_as_float(u & 0xffff0000u); }

// R17: SINGLE-BARRIER STEP. R15/R16 (pipelined poll) failed to compile twice
// and the mechanism's risk-adjusted gain was marginal (sample phases collapse
// in a bare spin loop; drain-at-exit eats the rest) -- axis abandoned.
// Fresh read of R14's loop: barrier S2's implicit s_waitcnt vmcnt(0) drains
// the x_{t+2} prefetch (L3/HBM latency!) and the publish store-ack INTO the
// critical loop every step. S2's real dependencies (osc->y, x handoff) move
// to S1 of the next iteration:
//   - osc[2][8][2] parity buffers; tid0 sums osc[(t-1)&1] -> y[t-2] after
//     S1(t) (writers reached S1(t) after their slack writes; next same-parity
//     overwrite is after S1(t+1), which tid0 reaches only after its read).
//   - h_lds[2][4096] parity buffers; same-parity rewrite (step t+2) is gated
//     by POLL(t+2) => all rows gen t+2 => every WG passed S1(t+1) => our
//     slowest wave published t+1 => its step-t reads are done. The gen chain
//     itself orders LDS reuse.
//   - x buffers already safe across S1 (write post-S1(t), last read pre-S1(t)).
// Net: one barrier less, and the x-prefetch + store-ack drains fold into the
// next poll's own vmcnt(0) wait (time we'd spend polling anyway).
// Poll/publish/protocol byte-identical to R14 (11.35 ms): 16-B granules,
// tag-in-mantissa (2 bits; WG skew <=2 gens so t vs t-2 differ mod 4),
// immediate lane0/1 publish, x 2-ahead prefetch.
__global__ __launch_bounds__(512, 2) void snn_persistent(
    const float* __restrict__ x, const float* __restrict__ Win,
    const float* __restrict__ Wrec, const float* __restrict__ Wout,
    const float* __restrict__ gbias, float* __restrict__ y,
    unsigned* __restrict__ hbuf)
{
    __shared__ __attribute__((aligned(16))) float h_lds[2][H_DIM];  // 32 KB
    __shared__ __attribute__((aligned(16))) float xb0[IN_DIM];      // 4 KB
    __shared__ __attribute__((aligned(16))) float xb1[IN_DIM];      // 4 KB
    __shared__ float osc[2][8][2];

    const int tid = threadIdx.x;
    const int w   = tid >> 6;     // wave 0..7
    const int l   = tid & 63;     // lane
    const int wg  = blockIdx.x;   // 0..255

    const int rowA  = wg * 16 + w;      // both W_rec rows register-resident
    const int rowB  = rowA + 8;
    const int orow0 = wg * 2;
    const int orow1 = orow0 + 1;

    // ---- one-time: 32 register-resident W_rec row-slices (128 VGPRs) ----
    const float4* pa = (const float4*)Wrec + (size_t)rowA * (H_DIM / 4) + l;
    const float4* pb = (const float4*)Wrec + (size_t)rowB * (H_DIM / 4) + l;
#define WRL(k) float4 wa##k = pa[(k) * 64]; PIN4(wa##k); \
               float4 wb##k = pb[(k) * 64]; PIN4(wb##k);
    WRL(0) WRL(1) WRL(2) WRL(3) WRL(4) WRL(5) WRL(6) WRL(7)
    WRL(8) WRL(9) WRL(10) WRL(11) WRL(12) WRL(13) WRL(14) WRL(15)
#undef WRL

    const float4* pia = (const float4*)Win + (size_t)rowA * (IN_DIM / 4) + l;
    const float4* pib = (const float4*)Win + (size_t)rowB * (IN_DIM / 4) + l;
    unsigned wiA[8], wiB[8];
    #pragma unroll
    for (int k = 0; k < 4; ++k) {
        float4 va = pia[k * 64], vb = pib[k * 64];
        wiA[2 * k]     = pack_bf2(va.x, va.y);
        wiA[2 * k + 1] = pack_bf2(va.z, va.w);
        wiB[2 * k]     = pack_bf2(vb.x, vb.y);
        wiB[2 * k + 1] = pack_bf2(vb.z, vb.w);
    }

    // W_out taps for the granule layout: thread owns rows 4tid+2048g+j,
    // g=0..1, j=0..3 (matching the dwordx4 poll granules below).
    const float* po0b = Wout + (size_t)orow0 * H_DIM + 4 * tid;
    const float* po1b = Wout + (size_t)orow1 * H_DIM + 4 * tid;
    unsigned woP0[4], woP1[4];
    #pragma unroll
    for (int g = 0; g < 2; ++g)
        #pragma unroll
        for (int m = 0; m < 2; ++m) {
            woP0[2 * g + m] = pack_bf2(po0b[2048 * g + 2 * m],
                                       po0b[2048 * g + 2 * m + 1]);
            woP1[2 * g + m] = pack_bf2(po1b[2048 * g + 2 * m],
                                       po1b[2048 * g + 2 * m + 1]);
        }

    const float gbA  = gbias[rowA];
    const float gbB  = gbias[rowB];
    const float leak = 0.1f;

    // hbuf: [parity][H_DIM] u32, tag = low 2 bits (memset 0 => gen0, h0=0).
    unsigned* h32_0 = hbuf;           // even gens
    unsigned* h32_1 = hbuf + H_DIM;   // odd gens

    float iA, iB;            // input currents, computed one step ahead
#define COMPUTE_I(XB) do { iA = 0.f; iB = 0.f;                                  \
        const float4* x4_ = (const float4*)(XB);                                \
        _Pragma("unroll")                                                       \
        for (int k = 0; k < 4; ++k) {                                           \
            float4 xv = x4_[k * 64 + l];                                        \
            unsigned a0 = wiA[2 * k], a1 = wiA[2 * k + 1];                      \
            unsigned c0 = wiB[2 * k], c1 = wiB[2 * k + 1];                      \
            iA = fmaf(bf_lo(a0), xv.x, fmaf(bf_hi(a0), xv.y,                    \
                 fmaf(bf_lo(a1), xv.z, fmaf(bf_hi(a1), xv.w, iA))));            \
            iB = fmaf(bf_lo(c0), xv.x, fmaf(bf_hi(c0), xv.y,                    \
                 fmaf(bf_lo(c1), xv.z, fmaf(bf_hi(c1), xv.w, iB))));            \
        }                                                                       \
        _Pragma("unroll")                                                       \
        for (int off = 32; off; off >>= 1) {                                    \
            iA += __shfl_xor(iA, off); iB += __shfl_xor(iB, off);               \
        } } while (0)

    uint4 g0, g1;            // this thread's 2 accepted 4-row granules
    // R14-proven masked sweep: 2 16-B granules; per-4B tags make non-atomic
    // vector loads safe; sc0 sc1 bypasses L1 + non-coherent XCD L2.
#define POLL_STAGE(SRC32, GEN) do { unsigned pend = 0x3u;                       \
        const unsigned tag_ = (unsigned)(GEN) & 3u;                             \
        const uint4* s4_ = (const uint4*)(SRC32);                               \
        const uint4* p0_ = s4_ + tid;                                           \
        const uint4* p1_ = s4_ + tid + 512;                                     \
        while (pend) {                                                          \
            uint4 q0_, q1_;                                                     \
            asm volatile(                                                       \
                "global_load_dwordx4 %0, %2, off sc0 sc1\n\t"                   \
                "global_load_dwordx4 %1, %3, off sc0 sc1\n\t"                   \
                "s_waitcnt vmcnt(0)"                                            \
                : "=&v"(q0_), "=&v"(q1_)                                        \
                : "v"(p0_), "v"(p1_)                                            \
                : "memory");                                                    \
            if (pend & 1u) {                                                    \
                unsigned m_ = ((q0_.x ^ tag_) | (q0_.y ^ tag_) |                \
                               (q0_.z ^ tag_) | (q0_.w ^ tag_)) & 3u;           \
                if (m_ == 0u) { g0 = q0_; pend &= ~1u; }                        \
            }                                                                   \
            if (pend & 2u) {                                                    \
                unsigned m_ = ((q1_.x ^ tag_) | (q1_.y ^ tag_) |                \
                               (q1_.z ^ tag_) | (q1_.w ^ tag_)) & 3u;           \
                if (m_ == 0u) { g1 = q1_; pend &= ~2u; }                        \
            }                                                                   \
            if (pend) __builtin_amdgcn_s_sleep(1);  /* ~64cy backoff */         \
        } } while (0)

    // W_out partials straight from granules (g covers rows 4tid+2048g+0..3);
    // writes the given osc parity buffer.
#define WOUT_OSC(OSCP) do { float p0 = 0.f, p1 = 0.f;                           \
        float v0_[4] = { __uint_as_float(g0.x), __uint_as_float(g0.y),          \
                         __uint_as_float(g0.z), __uint_as_float(g0.w) };        \
        float v1_[4] = { __uint_as_float(g1.x), __uint_as_float(g1.y),          \
                         __uint_as_float(g1.z), __uint_as_float(g1.w) };        \
        _Pragma("unroll")                                                       \
        for (int m = 0; m < 2; ++m) {                                           \
            p0 = fmaf(bf_lo(woP0[m]), v0_[2 * m],                               \
                 fmaf(bf_hi(woP0[m]), v0_[2 * m + 1], p0));                     \
            p0 = fmaf(bf_lo(woP0[2 + m]), v1_[2 * m],                           \
                 fmaf(bf_hi(woP0[2 + m]), v1_[2 * m + 1], p0));                 \
            p1 = fmaf(bf_lo(woP1[m]), v0_[2 * m],                               \
                 fmaf(bf_hi(woP1[m]), v0_[2 * m + 1], p1));                     \
            p1 = fmaf(bf_lo(woP1[2 + m]), v1_[2 * m],                           \
                 fmaf(bf_hi(woP1[2 + m]), v1_[2 * m + 1], p1));                 \
        }                                                                       \
        _Pragma("unroll")                                                       \
        for (int off = 32; off; off >>= 1) {                                    \
            p0 += __shfl_xor(p0, off); p1 += __shfl_xor(p1, off);               \
        }                                                                       \
        if (l == 0) { (OSCP)[w][0] = p0; (OSCP)[w][1] = p1; } } while (0)

    // ---- prologue: x_0,x_1 staged (2-ahead pipeline), I(t=0) ----
    if (tid < 256) {
        ((float4*)xb0)[tid] = ((const float4*)x)[tid];
        ((float4*)xb1)[tid] = ((const float4*)(x + IN_DIM))[tid];
    }
    __syncthreads();
    COMPUTE_I(xb0);

    #pragma unroll 1
    for (int t = 0; t < T_STEPS; ++t) {
        const unsigned* s32 = (t & 1) ? h32_1 : h32_0;
        unsigned*       d32 = (t & 1) ? h32_0 : h32_1;   // gen t+1's buffer
        float*          hb  = h_lds[t & 1];              // parity LDS buffer

        // ---- the poll IS the grid barrier AND the h staging load ----
        POLL_STAGE(s32, (unsigned)t);
        ((uint4*)hb)[tid]       = g0;   // rows 4tid   .. 4tid+3
        ((uint4*)hb)[tid + 512] = g1;   // rows +2048  .. +2051
        __syncthreads();                          // S1: h_t fully staged

        // ---- deferred y-store: osc[(t-1)&1] holds y[t-2] partials, written
        // in step t-1's slack; every writer passed S1(t) => ordered. ----
        if (t >= 2 && tid == 0) {
            const float (*op)[2] = osc[(t - 1) & 1];
            float s0 = 0.f, s1 = 0.f;
            #pragma unroll
            for (int q = 0; q < 8; ++q) { s0 += op[q][0]; s1 += op[q][1]; }
            y[(size_t)(t - 2) * O_DIM + orow0] = s0;
            y[(size_t)(t - 2) * O_DIM + orow1] = s1;
        }

        // ---- CRITICAL PATH: W_rec . h -> reduce -> nonlinearity -> publish
        float4 a = make_float4(0.f, 0.f, 0.f, 0.f);
        float4 b = make_float4(0.f, 0.f, 0.f, 0.f);
        {
            const float4* h4 = (const float4*)hb;
#define WRF(k) { float4 hv = h4[(k) * 64 + l];                                  \
                 a.x = fmaf(wa##k.x, hv.x, a.x); a.y = fmaf(wa##k.y, hv.y, a.y);\
                 a.z = fmaf(wa##k.z, hv.z, a.z); a.w = fmaf(wa##k.w, hv.w, a.w);\
                 b.x = fmaf(wb##k.x, hv.x, b.x); b.y = fmaf(wb##k.y, hv.y, b.y);\
                 b.z = fmaf(wb##k.z, hv.z, b.z); b.w = fmaf(wb##k.w, hv.w, b.w); }
            WRF(0) WRF(1) WRF(2) WRF(3) WRF(4) WRF(5) WRF(6) WRF(7)
            WRF(8) WRF(9) WRF(10) WRF(11) WRF(12) WRF(13) WRF(14) WRF(15)
#undef WRF
        }
        float rA = (a.x + a.y) + (a.z + a.w);
        float rB = (b.x + b.y) + (b.z + b.w);
        #pragma unroll
        for (int off = 32; off; off >>= 1) {
            rA += __shfl_xor(rA, off);
            rB += __shfl_xor(rB, off);
        }
        const unsigned tagn = (unsigned)(t + 1) & 3u;
        if (l == 0) {                             // immediate tagged publish
            float gA = sigmoid_f(gbA + rA);
            float zA = tanh_f(fmaf(gA, rA, iA));
            float hA = hb[rowA];
            unsigned hv = (__float_as_uint(fmaf(leak, zA - hA, hA)) & ~3u) | tagn;
            __hip_atomic_store(&d32[rowA], hv,
                               __ATOMIC_RELAXED, __HIP_MEMORY_SCOPE_AGENT);
        } else if (l == 1) {
            float gB = sigmoid_f(gbB + rB);
            float zB = tanh_f(fmaf(gB, rB, iB));
            float hB = hb[rowB];
            unsigned hv = (__float_as_uint(fmaf(leak, zB - hB, hB)) & ~3u) | tagn;
            __hip_atomic_store(&d32[rowB], hv,
                               __ATOMIC_RELAXED, __HIP_MEMORY_SCOPE_AGENT);
        }

        // ---- SLACK (h' in flight, NO second barrier): x two-ahead (drains
        // inside next poll's vmcnt wait), W_out partials, next W_in ----
        if (t + 2 < T_STEPS && tid < 256) {
            float* xbn = (t & 1) ? xb1 : xb0;     // buffer for x_{t+2}
            ((float4*)xbn)[tid] =
                ((const float4*)(x + (size_t)(t + 2) * IN_DIM))[tid];
        }
        if (t >= 1) WOUT_OSC(osc[t & 1]);         // y_{t-1} partials
        if (t + 1 < T_STEPS) {                    // I for t+1 from x_{t+1}
            const float* xbc = (t & 1) ? xb0 : xb1;
            COMPUTE_I(xbc);
        }
    }

    // ---- epilogue: y[T-2] from osc[1] (written step T-1), y[T-1] from h_T
    // (gen T sits in h32_0, T even) ----
    POLL_STAGE(h32_0, (unsigned)T_STEPS);
    __syncthreads();   // all step-(T-1) osc writes complete
    if (tid == 0) {
        const float (*op)[2] = osc[1];
        float s0 = 0.f, s1 = 0.f;
        #pragma unroll
        for (int q = 0; q < 8; ++q) { s0 += op[q][0]; s1 += op[q][1]; }
        y[(size_t)(T_STEPS - 2) * O_DIM + orow0] = s0;
        y[(size_t)(T_STEPS - 2) * O_DIM + orow1] = s1;
    }
    WOUT_OSC(osc[0]);
    __syncthreads();
    if (tid == 0) {
        const float (*op)[2] = osc[0];
        float s0 = 0.f, s1 = 0.f;
        #pragma unroll
        for (int q = 0; q < 8; ++q) { s0 += op[q][0]; s1 += op[q][1]; }
        y[(size_t)(T_STEPS - 1) * O_DIM + orow0] = s0;
        y[(size_t)(T_STEPS - 1) * O_DIM + orow1] = s1;
    }
}

extern "C" void kernel_launch(void* const* d_in, const int* in_sizes, int n_in,
                              void* d_out, int out_size, void* d_ws, size_t ws_size,
                              hipStream_t stream) {
    const float* x     = (const float*)d_in[0];
    const float* Win   = (const float*)d_in[1];
    const float* Wrec  = (const float*)d_in[2];
    const float* Wout  = (const float*)d_in[3];
    const float* gbias = (const float*)d_in[4];
    float* y = (float*)d_out;

    unsigned* hbuf = (unsigned*)d_ws;  // [2][H_DIM] tagged u32 = 32 KB

    // ws is re-poisoned before every replay: zero => h0 = 0 with tag 0.
    hipMemsetAsync(d_ws, 0, 2 * H_DIM * sizeof(unsigned), stream);

    void* args[] = { (void*)&x, (void*)&Win, (void*)&Wrec, (void*)&Wout,
                     (void*)&gbias, (void*)&y, (void*)&hbuf };
    hipLaunchCooperativeKernel((const void*)snn_persistent, dim3(N_WG), dim3(512),
                               args, 0, stream);
}